// Round 3
// baseline (460.399 us; speedup 1.0000x reference)
//
#include <hip/hip_runtime.h>

#define B_ 8
#define N_ 512
#define D_ 256
#define H_ 8
#define HD_ 32
#define E_ 8192
#define EA_ 32

// log(1e-6)
#define LOG1EM6 -13.815510557964274f
// 1/sqrt(32)
#define SCALE 0.17677669529663687f

// ---------------------------------------------------------------------------
// Kernel 1: QKV projection GEMM.  x:(B*N,256) @ W:(256,768) + b
// 64x64 tile, 256 threads, 4x4 per thread -> 768 blocks, ~3 blocks/CU.
// Output scattered into qkv[3][B][H][N][HD] so K/V panels are contiguous.
// ---------------------------------------------------------------------------
__global__ __launch_bounds__(256) void qkv_gemm(
    const float* __restrict__ x, const float* __restrict__ W,
    const float* __restrict__ bias, float* __restrict__ qkv)
{
    __shared__ float As[16][64];
    __shared__ float Bs[16][64];
    const int tid = threadIdx.x;
    const int m0 = blockIdx.y * 64;
    const int n0 = blockIdx.x * 64;
    const int tx = tid & 15, ty = tid >> 4;

    float acc[4][4];
#pragma unroll
    for (int i = 0; i < 4; i++)
#pragma unroll
        for (int j = 0; j < 4; j++) acc[i][j] = 0.0f;

    for (int kc = 0; kc < 256; kc += 16) {
        {   // A tile: 64 rows x 16 k  (transpose into As[k][row])
            int r  = tid >> 2;            // 0..63
            int c4 = tid & 3;             // k-quad
            float4 v = *(const float4*)&x[(m0 + r) * 256 + kc + c4 * 4];
            As[c4 * 4 + 0][r] = v.x;
            As[c4 * 4 + 1][r] = v.y;
            As[c4 * 4 + 2][r] = v.z;
            As[c4 * 4 + 3][r] = v.w;
        }
        {   // B tile: 16 k x 64 cols
            int kr = tid >> 4;            // 0..15
            int c4 = tid & 15;            // 0..15
            *(float4*)&Bs[kr][c4 * 4] =
                *(const float4*)&W[(kc + kr) * 768 + n0 + c4 * 4];
        }
        __syncthreads();
#pragma unroll
        for (int k = 0; k < 16; k++) {
            float a[4], bb[4];
            *(float4*)&a[0]  = *(float4*)&As[k][ty * 4];
            *(float4*)&bb[0] = *(float4*)&Bs[k][tx * 4];
#pragma unroll
            for (int i = 0; i < 4; i++)
#pragma unroll
                for (int j = 0; j < 4; j++) acc[i][j] += a[i] * bb[j];
        }
        __syncthreads();
    }

    const int col0  = n0 + tx * 4;
    const int which = col0 >> 8;
    const int h     = (col0 >> 5) & 7;
    const int hd0   = col0 & 31;
#pragma unroll
    for (int i = 0; i < 4; i++) {
        int row = m0 + ty * 4 + i;
        int b = row >> 9, n = row & 511;
        float* dst = qkv + (((size_t)(which * B_ + b) * H_ + h) * N_ + n) * HD_ + hd0;
#pragma unroll
        for (int j = 0; j < 4; j++) dst[j] = acc[i][j] + bias[col0 + j];
    }
}

// ---------------------------------------------------------------------------
// Kernel 2: per-edge modified focus log + scatter-winner selection.
// ---------------------------------------------------------------------------
__global__ __launch_bounds__(256) void edge_kernel(
    const float* __restrict__ edge_attr, const int* __restrict__ edge_index,
    const float* __restrict__ adj,
    const float* __restrict__ ds_W, const float* __restrict__ ds_b,
    const float* __restrict__ dw_W, const float* __restrict__ dw_b,
    const float* __restrict__ shifts, const float* __restrict__ widths,
    float* __restrict__ mlog, int* __restrict__ sel)
{
    __shared__ float ea[256 * 33];
    __shared__ float dsW[256], dwW[256];
    const int tid = threadIdx.x;
    const int b   = blockIdx.x >> 5;
    const int e0  = (blockIdx.x & 31) * 256;

    const float* eabase = edge_attr + ((size_t)b * E_ + e0) * EA_;
#pragma unroll
    for (int it = 0; it < 32; it++) {
        int i = tid + it * 256;
        ea[(i >> 5) * 33 + (i & 31)] = eabase[i];
    }
    dsW[tid] = ds_W[tid];
    dwW[tid] = dw_W[tid];
    __syncthreads();

    const int e  = e0 + tid;
    const int eu = edge_index[(size_t)b * 2 * E_ + e];
    const int ev = edge_index[(size_t)b * 2 * E_ + E_ + e];
    const float d = adj[((size_t)b * N_ + eu) * N_ + ev];

    float ds[8], dw[8];
#pragma unroll
    for (int h = 0; h < 8; h++) { ds[h] = ds_b[h]; dw[h] = dw_b[h]; }
#pragma unroll
    for (int k = 0; k < 32; k++) {
        float a = ea[tid * 33 + k];
#pragma unroll
        for (int h = 0; h < 8; h++) {
            ds[h] += a * dsW[k * 8 + h];
            dw[h] += a * dwW[k * 8 + h];
        }
    }
#pragma unroll
    for (int h = 0; h < 8; h++) {
        float ms = shifts[h] + ds[h];
        float mw = widths[h] + dw[h];
        float t  = d - ms;
        float ml = fmaxf(-(t * t) / (2.0f * mw * mw + 1e-6f), LOG1EM6);
        mlog[((size_t)(b * H_ + h)) * E_ + e] = ml;
    }
    atomicMax(&sel[((size_t)b * N_ + eu) * N_ + ev], e);
}

// ---------------------------------------------------------------------------
// lane reduction helper: fold 2*CNT partials across lane-pairs at XOR=MASK
// ---------------------------------------------------------------------------
template <int CNT, int MASK>
__device__ __forceinline__ void red_stage(float* part, int lane)
{
    const bool up = (lane & MASK) != 0;
#pragma unroll
    for (int k = 0; k < CNT; k++) {
        float send = up ? part[k] : part[k + CNT];
        float recv = __shfl_xor(send, MASK, 64);
        part[k] = (up ? part[k + CNT] : part[k]) + recv;
    }
}

// ---------------------------------------------------------------------------
// Kernel 3 v3: fused scores + focus/override/self-loop + softmax + PV.
// 512 threads (8 waves), 64 rows/block, 2-row groups.
//  - V in LDS, d4-major [8][512][4] = 64KB exactly (conflict-free reads)
//  - K streamed from global/L2, j-outer (coalesced 128B rows, k4 = 4 regs)
//  - Q via wave-uniform scalar loads (SGPRs, zero VGPR cost)
// Peak live set ~110 VGPR -> hope for <=128 => 2 blocks/CU = 4 waves/SIMD.
// NO launch_bounds occupancy forcing (round-2 spill lesson).
// ---------------------------------------------------------------------------
__global__ __launch_bounds__(512) void attn_kernel(
    const float* __restrict__ qkv, const float* __restrict__ adj,
    const float* __restrict__ mlog, const int* __restrict__ sel,
    const float* __restrict__ shifts, const float* __restrict__ widths,
    const float* __restrict__ slw_arr, float* __restrict__ out)
{
    extern __shared__ float V_lds[];        // [8][512][4] floats = 64KB

    const int tid = threadIdx.x;
    const int bid = blockIdx.x;             // b*64 + h*8 + rt
    const int b  = bid >> 6;
    const int h  = (bid >> 3) & 7;
    const int rt = bid & 7;
    const int u0 = rt * 64;

    const float* Kg = qkv + ((size_t)(1 * B_ + b) * H_ + h) * N_ * HD_;
    const float* Vg = qkv + ((size_t)(2 * B_ + b) * H_ + h) * N_ * HD_;
    const float* Qg = qkv + ((size_t)(0 * B_ + b) * H_ + h) * N_ * HD_;

    // stage V into LDS, d4-major (write conflicts 8-way, once, negligible)
#pragma unroll
    for (int it = 0; it < 8; it++) {
        int idx = tid + it * 512;           // 0..4095 float4s
        int v  = idx >> 3;
        int d4 = idx & 7;
        float4 val = ((const float4*)Vg)[idx];
        *(float4*)&V_lds[d4 * 2048 + v * 4] = val;
    }
    __syncthreads();

    const float s_h   = shifts[h];
    const float w_h   = widths[h];
    const float inv2w = 1.0f / (2.0f * w_h * w_h + 1e-6f);
    const float slw   = slw_arr[h];

    const int wv   = tid >> 6;              // 0..7
    const int lane = tid & 63;
    const float* mlg = mlog + ((size_t)(b * H_ + h)) * E_;

    for (int g = 0; g < 4; g++) {
        // global row index of row 0 of this group — wave-uniform
        const int ul0 = __builtin_amdgcn_readfirstlane(u0 + wv * 8 + g * 2);
        const float* Q0 = Qg + ul0 * 32;    // uniform -> scalar loads
        const float* Q1 = Q0 + 32;

        // prefetch adj + sel for the 2 rows (in flight under QK^T)
        float adjv[2][8];
        int   selv[2][8];
#pragma unroll
        for (int r = 0; r < 2; r++) {
            const float* arow = adj + ((size_t)b * N_ + ul0 + r) * N_;
            const int*   srow = sel + ((size_t)b * N_ + ul0 + r) * N_;
#pragma unroll
            for (int j = 0; j < 8; j++) {
                adjv[r][j] = arow[lane + 64 * j];
                selv[r][j] = srow[lane + 64 * j];
            }
        }

        // QK^T: j-outer, each lane streams one contiguous 128B K row per j
        float acc[2][8];
#pragma unroll
        for (int j = 0; j < 8; j++) {
            const float* Krow = Kg + (size_t)(lane + 64 * j) * 32;
            float a0 = 0.0f, a1 = 0.0f;
#pragma unroll
            for (int d4 = 0; d4 < 8; d4++) {
                float4 k4 = *(const float4*)&Krow[d4 * 4];
                float4 q0 = *(const float4*)&Q0[d4 * 4];   // SGPR broadcast
                float4 q1 = *(const float4*)&Q1[d4 * 4];
                a0 += q0.x * k4.x + q0.y * k4.y + q0.z * k4.z + q0.w * k4.w;
                a1 += q1.x * k4.x + q1.y * k4.y + q1.z * k4.z + q1.w * k4.w;
            }
            acc[0][j] = a0;
            acc[1][j] = a1;
        }

        // adjust + softmax for both rows (independent chains interleave)
        float p[2][8];
#pragma unroll
        for (int r = 0; r < 2; r++) {
            const int u = ul0 + r;
            float af[8];
#pragma unroll
            for (int j = 0; j < 8; j++) {
                float a = acc[r][j] * SCALE;
                int   sv = selv[r][j];
                float ov;
                if (sv >= 0) {
                    ov = mlg[sv];           // edge override (replaces baseline)
                } else {
                    float t = adjv[r][j] - s_h;
                    ov = fmaxf(-(t * t) * inv2w, LOG1EM6);
                }
                a += ov;
                if (lane + 64 * j == u) a += slw;   // self-loop
                af[j] = a;
            }
            float m = af[0];
#pragma unroll
            for (int j = 1; j < 8; j++) m = fmaxf(m, af[j]);
#pragma unroll
            for (int mk = 32; mk >= 1; mk >>= 1)
                m = fmaxf(m, __shfl_xor(m, mk, 64));
            float ssum = 0.0f;
#pragma unroll
            for (int j = 0; j < 8; j++) {
                p[r][j] = __expf(af[j] - m);
                ssum += p[r][j];
            }
#pragma unroll
            for (int mk = 32; mk >= 1; mk >>= 1)
                ssum += __shfl_xor(ssum, mk, 64);
            const float pinv = 1.0f / ssum;
#pragma unroll
            for (int j = 0; j < 8; j++) p[r][j] *= pinv;
        }

        // PV for both rows sharing each V read (d4-major LDS, conflict-free)
        float part0[32], part1[32];
#pragma unroll
        for (int d = 0; d < 32; d++) { part0[d] = 0.0f; part1[d] = 0.0f; }
#pragma unroll
        for (int d4 = 0; d4 < 8; d4++) {
#pragma unroll
            for (int j = 0; j < 8; j++) {
                float4 v4 = *(float4*)&V_lds[d4 * 2048 + (lane + 64 * j) * 4];
                part0[d4 * 4 + 0] += p[0][j] * v4.x;
                part0[d4 * 4 + 1] += p[0][j] * v4.y;
                part0[d4 * 4 + 2] += p[0][j] * v4.z;
                part0[d4 * 4 + 3] += p[0][j] * v4.w;
                part1[d4 * 4 + 0] += p[1][j] * v4.x;
                part1[d4 * 4 + 1] += p[1][j] * v4.y;
                part1[d4 * 4 + 2] += p[1][j] * v4.z;
                part1[d4 * 4 + 3] += p[1][j] * v4.w;
            }
        }
        // reduce 32 dims across 64 lanes for both rows (chains interleave)
        red_stage<16, 32>(part0, lane);  red_stage<16, 32>(part1, lane);
        red_stage<8, 16>(part0, lane);   red_stage<8, 16>(part1, lane);
        red_stage<4, 8>(part0, lane);    red_stage<4, 8>(part1, lane);
        red_stage<2, 4>(part0, lane);    red_stage<2, 4>(part1, lane);
        red_stage<1, 2>(part0, lane);    red_stage<1, 2>(part1, lane);
        // final: even lane keeps row0, odd lane keeps row1 -> all lanes store
        float send = (lane & 1) ? part0[0] : part1[0];
        float recv = __shfl_xor(send, 1, 64);
        float keep = (lane & 1) ? part1[0] : part0[0];
        float tot  = keep + recv;
        int   dd   = lane >> 1;
        int   urow = ul0 + (lane & 1);
        out[((size_t)b * N_ + urow) * D_ + h * HD_ + dd] = tot;
    }
}

// ---------------------------------------------------------------------------
extern "C" void kernel_launch(void* const* d_in, const int* in_sizes, int n_in,
                              void* d_out, int out_size, void* d_ws, size_t ws_size,
                              hipStream_t stream)
{
    const float* x          = (const float*)d_in[0];
    const float* adj        = (const float*)d_in[1];
    const int*   edge_index = (const int*)d_in[2];
    const float* edge_attr  = (const float*)d_in[3];
    const float* qkv_W      = (const float*)d_in[6];
    const float* qkv_b      = (const float*)d_in[7];
    const float* ds_W       = (const float*)d_in[12];
    const float* ds_b       = (const float*)d_in[13];
    const float* dw_W       = (const float*)d_in[14];
    const float* dw_b       = (const float*)d_in[15];
    const float* shifts     = (const float*)d_in[16];
    const float* widths     = (const float*)d_in[17];
    const float* slw        = (const float*)d_in[18];
    float* out = (float*)d_out;

    float* qkv  = (float*)d_ws;                              // 3*B*H*N*HD f32
    float* mlog = qkv + (size_t)3 * B_ * H_ * N_ * HD_;      // B*H*E f32
    int*   sel  = (int*)(mlog + (size_t)B_ * H_ * E_);       // B*N*N i32

    hipMemsetAsync(sel, 0xFF, (size_t)B_ * N_ * N_ * sizeof(int), stream);

    qkv_gemm<<<dim3(12, 64), 256, 0, stream>>>(x, qkv_W, qkv_b, qkv);

    edge_kernel<<<dim3(256), 256, 0, stream>>>(edge_attr, edge_index, adj,
                                               ds_W, ds_b, dw_W, dw_b,
                                               shifts, widths, mlog, sel);

    hipFuncSetAttribute((const void*)attn_kernel,
                        hipFuncAttributeMaxDynamicSharedMemorySize, 65536);
    attn_kernel<<<dim3(512), 512, 65536, stream>>>(qkv, adj, mlog, sel,
                                                   shifts, widths, slw, out);
}

// Round 4
// 218.100 us; speedup vs baseline: 2.1110x; 2.1110x over previous
//
#include <hip/hip_runtime.h>

#define B_ 8
#define N_ 512
#define D_ 256
#define H_ 8
#define HD_ 32
#define E_ 8192
#define EA_ 32

// log(1e-6)
#define LOG1EM6 -13.815510557964274f
// 1/sqrt(32)
#define SCALE 0.17677669529663687f

// ---------------------------------------------------------------------------
// Kernel 1: QKV projection GEMM.  x:(B*N,256) @ W:(256,768) + b
// 64x64 tile, 256 threads, 4x4 per thread -> 768 blocks, ~3 blocks/CU.
// Output scattered into qkv[3][B][H][N][HD] so K/V panels are contiguous.
// ---------------------------------------------------------------------------
__global__ __launch_bounds__(256) void qkv_gemm(
    const float* __restrict__ x, const float* __restrict__ W,
    const float* __restrict__ bias, float* __restrict__ qkv)
{
    __shared__ float As[16][64];
    __shared__ float Bs[16][64];
    const int tid = threadIdx.x;
    const int m0 = blockIdx.y * 64;
    const int n0 = blockIdx.x * 64;
    const int tx = tid & 15, ty = tid >> 4;

    float acc[4][4];
#pragma unroll
    for (int i = 0; i < 4; i++)
#pragma unroll
        for (int j = 0; j < 4; j++) acc[i][j] = 0.0f;

    for (int kc = 0; kc < 256; kc += 16) {
        {   // A tile: 64 rows x 16 k  (transpose into As[k][row])
            int r  = tid >> 2;            // 0..63
            int c4 = tid & 3;             // k-quad
            float4 v = *(const float4*)&x[(m0 + r) * 256 + kc + c4 * 4];
            As[c4 * 4 + 0][r] = v.x;
            As[c4 * 4 + 1][r] = v.y;
            As[c4 * 4 + 2][r] = v.z;
            As[c4 * 4 + 3][r] = v.w;
        }
        {   // B tile: 16 k x 64 cols
            int kr = tid >> 4;            // 0..15
            int c4 = tid & 15;            // 0..15
            *(float4*)&Bs[kr][c4 * 4] =
                *(const float4*)&W[(kc + kr) * 768 + n0 + c4 * 4];
        }
        __syncthreads();
#pragma unroll
        for (int k = 0; k < 16; k++) {
            float a[4], bb[4];
            *(float4*)&a[0]  = *(float4*)&As[k][ty * 4];
            *(float4*)&bb[0] = *(float4*)&Bs[k][tx * 4];
#pragma unroll
            for (int i = 0; i < 4; i++)
#pragma unroll
                for (int j = 0; j < 4; j++) acc[i][j] += a[i] * bb[j];
        }
        __syncthreads();
    }

    const int col0  = n0 + tx * 4;
    const int which = col0 >> 8;
    const int h     = (col0 >> 5) & 7;
    const int hd0   = col0 & 31;
#pragma unroll
    for (int i = 0; i < 4; i++) {
        int row = m0 + ty * 4 + i;
        int b = row >> 9, n = row & 511;
        float* dst = qkv + (((size_t)(which * B_ + b) * H_ + h) * N_ + n) * HD_ + hd0;
#pragma unroll
        for (int j = 0; j < 4; j++) dst[j] = acc[i][j] + bias[col0 + j];
    }
}

// ---------------------------------------------------------------------------
// Kernel 2: per-edge modified focus log + scatter-winner selection.
// ---------------------------------------------------------------------------
__global__ __launch_bounds__(256) void edge_kernel(
    const float* __restrict__ edge_attr, const int* __restrict__ edge_index,
    const float* __restrict__ adj,
    const float* __restrict__ ds_W, const float* __restrict__ ds_b,
    const float* __restrict__ dw_W, const float* __restrict__ dw_b,
    const float* __restrict__ shifts, const float* __restrict__ widths,
    float* __restrict__ mlog, int* __restrict__ sel)
{
    __shared__ float ea[256 * 33];
    __shared__ float dsW[256], dwW[256];
    const int tid = threadIdx.x;
    const int b   = blockIdx.x >> 5;
    const int e0  = (blockIdx.x & 31) * 256;

    const float* eabase = edge_attr + ((size_t)b * E_ + e0) * EA_;
#pragma unroll
    for (int it = 0; it < 32; it++) {
        int i = tid + it * 256;
        ea[(i >> 5) * 33 + (i & 31)] = eabase[i];
    }
    dsW[tid] = ds_W[tid];
    dwW[tid] = dw_W[tid];
    __syncthreads();

    const int e  = e0 + tid;
    const int eu = edge_index[(size_t)b * 2 * E_ + e];
    const int ev = edge_index[(size_t)b * 2 * E_ + E_ + e];
    const float d = adj[((size_t)b * N_ + eu) * N_ + ev];

    float ds[8], dw[8];
#pragma unroll
    for (int h = 0; h < 8; h++) { ds[h] = ds_b[h]; dw[h] = dw_b[h]; }
#pragma unroll
    for (int k = 0; k < 32; k++) {
        float a = ea[tid * 33 + k];
#pragma unroll
        for (int h = 0; h < 8; h++) {
            ds[h] += a * dsW[k * 8 + h];
            dw[h] += a * dwW[k * 8 + h];
        }
    }
#pragma unroll
    for (int h = 0; h < 8; h++) {
        float ms = shifts[h] + ds[h];
        float mw = widths[h] + dw[h];
        float t  = d - ms;
        float ml = fmaxf(-(t * t) / (2.0f * mw * mw + 1e-6f), LOG1EM6);
        mlog[((size_t)(b * H_ + h)) * E_ + e] = ml;
    }
    atomicMax(&sel[((size_t)b * N_ + eu) * N_ + ev], e);
}

// ---------------------------------------------------------------------------
// lane reduction helper: fold 2*CNT partials across lane-pairs at XOR=MASK
// ---------------------------------------------------------------------------
template <int CNT, int MASK>
__device__ __forceinline__ void red_stage(float* part, int lane)
{
    const bool up = (lane & MASK) != 0;
#pragma unroll
    for (int k = 0; k < CNT; k++) {
        float send = up ? part[k] : part[k + CNT];
        float recv = __shfl_xor(send, MASK, 64);
        part[k] = (up ? part[k + CNT] : part[k]) + recv;
    }
}

// ---------------------------------------------------------------------------
// Kernel 3 v4: fused scores + focus/override/self-loop + softmax + PV.
// 256 threads (4 waves) + launch_bounds(256,1): compiler may use up to 256
// VGPR -> NO spills (round-2/3 lesson: 512-thr blocks get a 128-VGPR cap and
// spill to scratch: FETCH 55MB->1GB).
//  - Only V in LDS, round-1 stride-36 layout = 72KB -> 2 blocks/CU
//    (2 waves/SIMD, 2x round-1 latency hiding); staging conflict-free.
//  - K streamed from global/L2 (2-row groups share each 128B K row).
//  - Q via wave-uniform scalar loads (SGPRs, proven fit at SGPR=112).
// ---------------------------------------------------------------------------
__global__ __launch_bounds__(256, 1) void attn_kernel(
    const float* __restrict__ qkv, const float* __restrict__ adj,
    const float* __restrict__ mlog, const int* __restrict__ sel,
    const float* __restrict__ shifts, const float* __restrict__ widths,
    const float* __restrict__ slw_arr, float* __restrict__ out)
{
    extern __shared__ float V_lds[];        // [512][36] floats = 72KB

    const int tid = threadIdx.x;
    const int bid = blockIdx.x;             // b*64 + h*8 + rt
    const int b  = bid >> 6;
    const int h  = (bid >> 3) & 7;
    const int rt = bid & 7;
    const int u0 = rt * 64;

    const float* Kg = qkv + ((size_t)(1 * B_ + b) * H_ + h) * N_ * HD_;
    const float* Vg = qkv + ((size_t)(2 * B_ + b) * H_ + h) * N_ * HD_;
    const float* Qg = qkv + ((size_t)(0 * B_ + b) * H_ + h) * N_ * HD_;

    // stage V into LDS (round-1 pattern: conflict-free write & read)
#pragma unroll
    for (int it = 0; it < 16; it++) {
        int i4 = tid + it * 256;            // 0..4095 float4s
        int v  = i4 >> 3;
        int d4 = i4 & 7;
        *(float4*)&V_lds[v * 36 + d4 * 4] = ((const float4*)Vg)[i4];
    }
    __syncthreads();

    const float s_h   = shifts[h];
    const float w_h   = widths[h];
    const float inv2w = 1.0f / (2.0f * w_h * w_h + 1e-6f);
    const float slw   = slw_arr[h];

    const int wv   = tid >> 6;              // 0..3
    const int lane = tid & 63;
    const float* mlg = mlog + ((size_t)(b * H_ + h)) * E_;

    for (int g = 0; g < 8; g++) {
        // global row index of row 0 of this group — wave-uniform
        const int ul0 = __builtin_amdgcn_readfirstlane(u0 + wv * 16 + g * 2);
        const float* Q0 = Qg + ul0 * 32;    // uniform -> scalar loads
        const float* Q1 = Q0 + 32;

        // prefetch adj + sel for the 2 rows (in flight under QK^T)
        float adjv[2][8];
        int   selv[2][8];
#pragma unroll
        for (int r = 0; r < 2; r++) {
            const float* arow = adj + ((size_t)b * N_ + ul0 + r) * N_;
            const int*   srow = sel + ((size_t)b * N_ + ul0 + r) * N_;
#pragma unroll
            for (int j = 0; j < 8; j++) {
                adjv[r][j] = arow[lane + 64 * j];
                selv[r][j] = srow[lane + 64 * j];
            }
        }

        // QK^T: j-outer, each lane streams one contiguous 128B K row per j
        float acc[2][8];
#pragma unroll
        for (int j = 0; j < 8; j++) {
            const float* Krow = Kg + (size_t)(lane + 64 * j) * 32;
            float a0 = 0.0f, a1 = 0.0f;
#pragma unroll
            for (int d4 = 0; d4 < 8; d4++) {
                float4 k4 = *(const float4*)&Krow[d4 * 4];
                float4 q0 = *(const float4*)&Q0[d4 * 4];   // SGPR broadcast
                float4 q1 = *(const float4*)&Q1[d4 * 4];
                a0 += q0.x * k4.x + q0.y * k4.y + q0.z * k4.z + q0.w * k4.w;
                a1 += q1.x * k4.x + q1.y * k4.y + q1.z * k4.z + q1.w * k4.w;
            }
            acc[0][j] = a0;
            acc[1][j] = a1;
        }

        // adjust + softmax for both rows (independent chains interleave)
        float p[2][8];
#pragma unroll
        for (int r = 0; r < 2; r++) {
            const int u = ul0 + r;
            float af[8];
#pragma unroll
            for (int j = 0; j < 8; j++) {
                float a = acc[r][j] * SCALE;
                int   sv = selv[r][j];
                float ov;
                if (sv >= 0) {
                    ov = mlg[sv];           // edge override (replaces baseline)
                } else {
                    float t = adjv[r][j] - s_h;
                    ov = fmaxf(-(t * t) * inv2w, LOG1EM6);
                }
                a += ov;
                if (lane + 64 * j == u) a += slw;   // self-loop
                af[j] = a;
            }
            float m = af[0];
#pragma unroll
            for (int j = 1; j < 8; j++) m = fmaxf(m, af[j]);
#pragma unroll
            for (int mk = 32; mk >= 1; mk >>= 1)
                m = fmaxf(m, __shfl_xor(m, mk, 64));
            float ssum = 0.0f;
#pragma unroll
            for (int j = 0; j < 8; j++) {
                p[r][j] = __expf(af[j] - m);
                ssum += p[r][j];
            }
#pragma unroll
            for (int mk = 32; mk >= 1; mk >>= 1)
                ssum += __shfl_xor(ssum, mk, 64);
            const float pinv = 1.0f / ssum;
#pragma unroll
            for (int j = 0; j < 8; j++) p[r][j] *= pinv;
        }

        // PV for both rows sharing each V read (stride-36, conflict-free)
        float part0[32], part1[32];
#pragma unroll
        for (int d = 0; d < 32; d++) { part0[d] = 0.0f; part1[d] = 0.0f; }
#pragma unroll
        for (int d4 = 0; d4 < 8; d4++) {
#pragma unroll
            for (int j = 0; j < 8; j++) {
                float4 v4 = *(float4*)&V_lds[(lane + 64 * j) * 36 + d4 * 4];
                part0[d4 * 4 + 0] += p[0][j] * v4.x;
                part0[d4 * 4 + 1] += p[0][j] * v4.y;
                part0[d4 * 4 + 2] += p[0][j] * v4.z;
                part0[d4 * 4 + 3] += p[0][j] * v4.w;
                part1[d4 * 4 + 0] += p[1][j] * v4.x;
                part1[d4 * 4 + 1] += p[1][j] * v4.y;
                part1[d4 * 4 + 2] += p[1][j] * v4.z;
                part1[d4 * 4 + 3] += p[1][j] * v4.w;
            }
        }
        // reduce 32 dims across 64 lanes for both rows (chains interleave)
        red_stage<16, 32>(part0, lane);  red_stage<16, 32>(part1, lane);
        red_stage<8, 16>(part0, lane);   red_stage<8, 16>(part1, lane);
        red_stage<4, 8>(part0, lane);    red_stage<4, 8>(part1, lane);
        red_stage<2, 4>(part0, lane);    red_stage<2, 4>(part1, lane);
        red_stage<1, 2>(part0, lane);    red_stage<1, 2>(part1, lane);
        // final: even lane keeps row0, odd lane keeps row1 -> all lanes store
        float send = (lane & 1) ? part0[0] : part1[0];
        float recv = __shfl_xor(send, 1, 64);
        float keep = (lane & 1) ? part1[0] : part0[0];
        float tot  = keep + recv;
        int   dd   = lane >> 1;
        int   urow = ul0 + (lane & 1);
        out[((size_t)b * N_ + urow) * D_ + h * HD_ + dd] = tot;
    }
}

// ---------------------------------------------------------------------------
extern "C" void kernel_launch(void* const* d_in, const int* in_sizes, int n_in,
                              void* d_out, int out_size, void* d_ws, size_t ws_size,
                              hipStream_t stream)
{
    const float* x          = (const float*)d_in[0];
    const float* adj        = (const float*)d_in[1];
    const int*   edge_index = (const int*)d_in[2];
    const float* edge_attr  = (const float*)d_in[3];
    const float* qkv_W      = (const float*)d_in[6];
    const float* qkv_b      = (const float*)d_in[7];
    const float* ds_W       = (const float*)d_in[12];
    const float* ds_b       = (const float*)d_in[13];
    const float* dw_W       = (const float*)d_in[14];
    const float* dw_b       = (const float*)d_in[15];
    const float* shifts     = (const float*)d_in[16];
    const float* widths     = (const float*)d_in[17];
    const float* slw        = (const float*)d_in[18];
    float* out = (float*)d_out;

    float* qkv  = (float*)d_ws;                              // 3*B*H*N*HD f32
    float* mlog = qkv + (size_t)3 * B_ * H_ * N_ * HD_;      // B*H*E f32
    int*   sel  = (int*)(mlog + (size_t)B_ * H_ * E_);       // B*N*N i32

    hipMemsetAsync(sel, 0xFF, (size_t)B_ * N_ * N_ * sizeof(int), stream);

    qkv_gemm<<<dim3(12, 64), 256, 0, stream>>>(x, qkv_W, qkv_b, qkv);

    edge_kernel<<<dim3(256), 256, 0, stream>>>(edge_attr, edge_index, adj,
                                               ds_W, ds_b, dw_W, dw_b,
                                               shifts, widths, mlog, sel);

    hipFuncSetAttribute((const void*)attn_kernel,
                        hipFuncAttributeMaxDynamicSharedMemorySize, 73728);
    attn_kernel<<<dim3(512), 256, 73728, stream>>>(qkv, adj, mlog, sel,
                                                   shifts, widths, slw, out);
}